// Round 3
// baseline (35.628 us; speedup 1.0000x reference)
//
#include <hip/hip_runtime.h>
#include <hip/hip_bf16.h>
#include <math.h>

#define WINDOW 50
#define BPT 256

typedef __attribute__((ext_vector_type(8))) short short8;
typedef __attribute__((ext_vector_type(4))) float f32x4;
typedef unsigned int uint;

union U8 { uint4 u; short8 s; };
__device__ inline short8 as_s8(uint4 u) { U8 t; t.u = u; return t.s; }

// pack (bf16(a) -> low16, bf16(b) -> high16), round-to-nearest-even
__device__ inline uint pk2(float a, float b) {
    uint r;
    asm("v_cvt_pk_bf16_f32 %0, %1, %2" : "=v"(r) : "v"(a), "v"(b));
    return r;
}
__device__ inline float lo_f32(uint u) { return __uint_as_float(u << 16); }
__device__ inline float hi_f32(uint u) { return __uint_as_float(u & 0xffff0000u); }

// wave-private LDS RAW fence: compiler ordering + HW wait (rule-18 pattern)
#define LDS_FENCE() do { asm volatile("s_waitcnt lgkmcnt(0)" ::: "memory"); \
                         __builtin_amdgcn_sched_barrier(0); } while (0)

// Design: thread = window for stats/L3/epilogue. All GEMMs computed transposed
// (C = W^T * X^T) so window = MFMA column (lane&15) at every layer; weights are
// constant A-fragments in VGPRs. stats+w1 split hi/lo packed in K-space (exact);
// w2 split hi/lo as 2 A-frag sets (exact in w2); h1 single bf16 (only rounding).
// L3 kept fp32 VALU per-thread. Wave-private LDS repacks, 2 block barriers.
__global__ __launch_bounds__(256) void nsg_kernel(
    const float* __restrict__ x,
    const float* __restrict__ w1, const float* __restrict__ b1,
    const float* __restrict__ w2, const float* __restrict__ b2,
    const float* __restrict__ w3, const float* __restrict__ b3,
    float* __restrict__ out, int B, int N, int M, int tiles)
{
    __shared__ float s_x[BPT + WINDOW + 2];   // 308 f32
    __shared__ f32x4 s_chunk[BPT + 40];       // 296 chunk moment-sums (10 elems each)
    __shared__ uint4 s_stat[4][64];           // per wave: split-packed stats per window
    __shared__ uint4 s_h1[4][128];            // per wave: 16 win x 128B (quarter, reused)
    __shared__ f32x4 s_h2[4][512];            // per wave: 64 win x 8 quads f32
    __shared__ f32x4 s_b1q[16];               // b1 as quads
    __shared__ f32x4 s_b2q[8];                // b2 as quads

    const int tid  = threadIdx.x;
    const int wv   = tid >> 6;
    const int wl   = tid & 63;
    const int l15  = wl & 15;
    const int g    = wl >> 4;
    const int tile = blockIdx.x % tiles;
    const int row  = blockIdx.x / tiles;
    const int m0   = tile * BPT;

    // ---- stage x (+halo) and biases ----
    const float* xr = x + (size_t)row * N;
    for (int i = tid; i < BPT + WINDOW; i += 256) {
        int gg = m0 + i;
        s_x[i] = (gg < N) ? xr[gg] : 0.0f;
    }
    if (tid < 16) s_b1q[tid] = ((const f32x4*)b1)[tid];
    if (tid < 8)  s_b2q[tid] = ((const f32x4*)b2)[tid];

    // ---- preload constant A-fragments (overlaps with barrier latency) ----
    // A1: w1^T, split hi/lo packed along K: k0-3 w1hi, k4-7 w1hi, k8-11 w1lo, k12-15 w1lo
    short8 A1[4];
    #pragma unroll
    for (int nt = 0; nt < 4; ++nt) {
        int n = nt * 16 + l15;
        float a = w1[0 * 64 + n], b = w1[1 * 64 + n];
        float c = w1[2 * 64 + n], d = w1[3 * 64 + n];
        uint hab = pk2(a, b), hcd = pk2(c, d);
        float la = a - lo_f32(hab), lb = b - hi_f32(hab);
        float lc = c - lo_f32(hcd), ld = d - hi_f32(hcd);
        uint lab = pk2(la, lb), lcd = pk2(lc, ld);
        uint4 u;
        if (g == 0)      u = make_uint4(hab, hcd, hab, hcd);
        else if (g == 1) u = make_uint4(lab, lcd, lab, lcd);
        else             u = make_uint4(0, 0, 0, 0);
        A1[nt] = as_s8(u);
    }
    // A2: w2^T (m=c, k=n), hi and lo fragment sets
    short8 A2h[2][2], A2l[2][2];
    #pragma unroll
    for (int mt = 0; mt < 2; ++mt) {
        int c = mt * 16 + l15;
        #pragma unroll
        for (int ks = 0; ks < 2; ++ks) {
            uint hu[4], lu[4];
            #pragma unroll
            for (int p = 0; p < 4; ++p) {
                int n = ks * 32 + g * 8 + 2 * p;
                float a = w2[n * 32 + c], b = w2[(n + 1) * 32 + c];
                uint h = pk2(a, b);
                float la = a - lo_f32(h), lb = b - hi_f32(h);
                hu[p] = h; lu[p] = pk2(la, lb);
            }
            A2h[mt][ks] = as_s8(make_uint4(hu[0], hu[1], hu[2], hu[3]));
            A2l[mt][ks] = as_s8(make_uint4(lu[0], lu[1], lu[2], lu[3]));
        }
    }
    __syncthreads();   // s_x ready

    // ---- chunk sums: C[t] = moments over x[t..t+10) ----
    f32x4 myC;
    {
        float S1 = 0.f, S2 = 0.f, S3 = 0.f, S4 = 0.f;
        #pragma unroll
        for (int i = 0; i < 10; ++i) {
            float v = s_x[tid + i], v2 = v * v;
            S1 += v; S2 += v2; S3 = fmaf(v2, v, S3); S4 = fmaf(v2, v2, S4);
        }
        myC = f32x4{S1, S2, S3, S4};
        s_chunk[tid] = myC;
    }
    if (tid < 40) {   // tail chunks 256..295
        float S1 = 0.f, S2 = 0.f, S3 = 0.f, S4 = 0.f;
        #pragma unroll
        for (int i = 0; i < 10; ++i) {
            float v = s_x[256 + tid + i], v2 = v * v;
            S1 += v; S2 += v2; S3 = fmaf(v2, v, S3); S4 = fmaf(v2, v2, S4);
        }
        s_chunk[256 + tid] = f32x4{S1, S2, S3, S4};
    }
    __syncthreads();   // chunks ready

    // ---- window moments from 5 chunks ----
    f32x4 ca = s_chunk[tid + 10], cb = s_chunk[tid + 20];
    f32x4 cc = s_chunk[tid + 30], cd = s_chunk[tid + 40];
    float S1 = myC[0] + ca[0] + cb[0] + cc[0] + cd[0];
    float S2 = myC[1] + ca[1] + cb[1] + cc[1] + cd[1];
    float S3 = myC[2] + ca[2] + cb[2] + cc[2] + cd[2];
    float S4 = myC[3] + ca[3] + cb[3] + cc[3] + cd[3];

    const float invW = 1.0f / (float)WINDOW;
    float mean = S1 * invW;
    float mu2  = mean * mean;
    float c2m = S2 - (float)WINDOW * mu2;
    float c3m = S3 - 3.0f * mean * S2 + 2.0f * (float)WINDOW * mu2 * mean;
    float c4m = S4 - 4.0f * mean * S3 + 6.0f * mu2 * S2
                  - 3.0f * (float)WINDOW * mu2 * mu2;
    float var    = c2m * (1.0f / (float)(WINDOW - 1));
    float sd     = sqrtf(var) + 1e-6f;
    float inv_sd = 1.0f / sd;
    float inv_sd2 = inv_sd * inv_sd;
    float skew = c3m * invW * inv_sd2 * inv_sd;
    float kurt = c4m * invW * inv_sd2 * inv_sd2;
    float center = s_x[tid + 25];

    // split-pack stats (hi,lo) -> exact MLP input
    {
        uint h01 = pk2(mean, sd), h23 = pk2(skew, kurt);
        float ml = mean - lo_f32(h01), sl = sd   - hi_f32(h01);
        float kl = skew - lo_f32(h23), ul = kurt - hi_f32(h23);
        uint l01 = pk2(ml, sl), l23 = pk2(kl, ul);
        s_stat[wv][wl] = make_uint4(h01, h23, l01, l23);
    }
    LDS_FENCE();

    uint2* ph1 = (uint2*)&s_h1[wv][0];

    // ---- per 16-window quarter: L1 MFMA -> repack -> L2 MFMA -> h2 to LDS ----
    #pragma unroll
    for (int wt = 0; wt < 4; ++wt) {
        int w = wt * 16 + l15;
        short8 B1 = as_s8(s_stat[wv][w]);   // 4-way same-addr broadcast

        f32x4 C1[4];
        #pragma unroll
        for (int nt = 0; nt < 4; ++nt) C1[nt] = s_b1q[nt * 4 + g];
        #pragma unroll
        for (int nt = 0; nt < 4; ++nt)
            C1[nt] = __builtin_amdgcn_mfma_f32_16x16x32_bf16(A1[nt], B1, C1[nt], 0, 0, 0);

        // repack h1 (relu, bf16) into B-fragment layout, wave-private
        #pragma unroll
        for (int nt = 0; nt < 4; ++nt) {
            uint p01 = pk2(fmaxf(C1[nt][0], 0.f), fmaxf(C1[nt][1], 0.f));
            uint p23 = pk2(fmaxf(C1[nt][2], 0.f), fmaxf(C1[nt][3], 0.f));
            int q = nt * 4 + g;
            uint2 t; t.x = p01; t.y = p23;
            ph1[(l15 * 16 + q) ^ ((l15 & 7) << 1)] = t;
        }
        LDS_FENCE();

        short8 B2k0 = as_s8(s_h1[wv][(l15 * 8 + 0 + g) ^ (l15 & 7)]);
        short8 B2k1 = as_s8(s_h1[wv][(l15 * 8 + 4 + g) ^ (l15 & 7)]);

        f32x4 C2[2];
        #pragma unroll
        for (int mt = 0; mt < 2; ++mt) C2[mt] = s_b2q[mt * 4 + g];
        #pragma unroll
        for (int mt = 0; mt < 2; ++mt) {
            C2[mt] = __builtin_amdgcn_mfma_f32_16x16x32_bf16(A2h[mt][0], B2k0, C2[mt], 0, 0, 0);
            C2[mt] = __builtin_amdgcn_mfma_f32_16x16x32_bf16(A2h[mt][1], B2k1, C2[mt], 0, 0, 0);
            C2[mt] = __builtin_amdgcn_mfma_f32_16x16x32_bf16(A2l[mt][0], B2k0, C2[mt], 0, 0, 0);
            C2[mt] = __builtin_amdgcn_mfma_f32_16x16x32_bf16(A2l[mt][1], B2k1, C2[mt], 0, 0, 0);
        }
        // relu(h2) -> LDS (f32, swizzled), indexed by window-in-wave
        #pragma unroll
        for (int mt = 0; mt < 2; ++mt) {
            f32x4 hq;
            #pragma unroll
            for (int j = 0; j < 4; ++j) hq[j] = fmaxf(C2[mt][j], 0.f);
            s_h2[wv][(w * 8 + mt * 4 + g) ^ (w & 7)] = hq;
        }
    }
    LDS_FENCE();

    // ---- L3 + epilogue per-thread (fp32) ----
    float gam = b3[0], bet = b3[1];
    #pragma unroll
    for (int q = 0; q < 8; ++q) {
        f32x4 h = s_h2[wv][(wl * 8 + q) ^ (wl & 7)];
        #pragma unroll
        for (int j = 0; j < 4; ++j) {
            int c = 16 * (q >> 2) + 4 * (q & 3) + j;
            gam = fmaf(h[j], w3[c * 2 + 0], gam);
            bet = fmaf(h[j], w3[c * 2 + 1], bet);
        }
    }

    const int m = m0 + tid;
    if (m < M)
        out[(size_t)row * M + m] = fmaf((center - mean) * inv_sd, gam, bet);
}

extern "C" void kernel_launch(void* const* d_in, const int* in_sizes, int n_in,
                              void* d_out, int out_size, void* d_ws, size_t ws_size,
                              hipStream_t stream) {
    const float* x  = (const float*)d_in[0];
    const float* w1 = (const float*)d_in[1];
    const float* b1 = (const float*)d_in[2];
    const float* w2 = (const float*)d_in[3];
    const float* b2 = (const float*)d_in[4];
    const float* w3 = (const float*)d_in[5];
    const float* b3 = (const float*)d_in[6];
    float* out = (float*)d_out;

    const int N = 32768;
    const int B = in_sizes[0] / N;           // 32
    const int M = N - WINDOW + 1;            // 32719
    const int tiles = (M + BPT - 1) / BPT;   // 128

    dim3 grid(B * tiles), block(BPT);
    nsg_kernel<<<grid, block, 0, stream>>>(x, w1, b1, w2, b2, w3, b3,
                                           out, B, N, M, tiles);
}

// Round 4
// 34.505 us; speedup vs baseline: 1.0325x; 1.0325x over previous
//
#include <hip/hip_runtime.h>
#include <hip/hip_bf16.h>
#include <math.h>

#define WINDOW 50

typedef __attribute__((ext_vector_type(8))) short short8;
typedef __attribute__((ext_vector_type(4))) float f32x4;
typedef unsigned int uint;

union U8 { uint4 u; short8 s; };
__device__ inline short8 as_s8(uint4 u) { U8 t; t.u = u; return t.s; }

// pack (bf16(a) -> low16, bf16(b) -> high16), RNE
__device__ inline uint pk2(float a, float b) {
    uint r;
    asm("v_cvt_pk_bf16_f32 %0, %1, %2" : "=v"(r) : "v"(a), "v"(b));
    return r;
}
__device__ inline float lo_f32(uint u) { return __uint_as_float(u << 16); }
__device__ inline float hi_f32(uint u) { return __uint_as_float(u & 0xffff0000u); }

// Transposed-GEMM design: C = W^T X^T so window = MFMA column at every layer.
// Exact everywhere: stats split packed in K-space, b1 K-packed (k16 x B=1.0),
// w2 split hi/lo (A2l in shared LDS), h1 split hi/lo (12 MFMA / quarter),
// L3 per-lane fp32 partials on C2 frags + shfl_xor reduce (no s_h2 buffer).
// 2 windows/thread (BPT=512). LDS layouts use PADDED strides (2 lanes/bank).
__global__ __launch_bounds__(256, 4) void nsg_kernel(
    const float* __restrict__ x,
    const float* __restrict__ w1, const float* __restrict__ b1,
    const float* __restrict__ w2, const float* __restrict__ b2,
    const float* __restrict__ w3, const float* __restrict__ b3,
    float* __restrict__ out, int N, int M, int tiles)
{
    __shared__ float s_x[564];           // 512 + 50 halo
    __shared__ f32x4 s_buf[1088];        // phase A: 552 chunk sums; phase B: per-wave h1 (272 f32x4 each)
    __shared__ uint4 s_a2l[4][64];       // w2-lo A-fragments [mt*2+ks][lane] (block-shared)
    __shared__ uint4 s_stat[4][128];     // per-wave split-packed stats [wv][set*64 + wl]

    const int tid = threadIdx.x;
    const int wv  = tid >> 6;
    const int wl  = tid & 63;
    const int l15 = wl & 15;
    const int g   = wl >> 4;
    const int tile = blockIdx.x % tiles;
    const int row  = blockIdx.x / tiles;
    const int m0   = tile * 512;

    // ---- stage x (+halo), clamped ----
    const float* xr = x + (size_t)row * N;
    for (int i = tid; i < 562; i += 256) {
        int gg = m0 + i;
        s_x[i] = (gg < N) ? xr[gg] : 0.0f;
    }

    // ---- one-time constant A-fragments ----
    // A1: w1^T; k0..7 (g=0)=w1hi|w1hi, k8..15 (g=1)=w1lo|w1lo (pairs stats hi|lo),
    // k16..17 (g=2)=(b1hi,b1lo) vs B=1.0, g=3 zero.
    short8 A1[4];
    #pragma unroll
    for (int nt = 0; nt < 4; ++nt) {
        int n = nt * 16 + l15;
        float a = w1[n], b = w1[64 + n], c = w1[128 + n], d = w1[192 + n];
        uint hab = pk2(a, b), hcd = pk2(c, d);
        uint lab = pk2(a - lo_f32(hab), b - hi_f32(hab));
        uint lcd = pk2(c - lo_f32(hcd), d - hi_f32(hcd));
        float bb = b1[n];
        uint bh = pk2(bb, 0.0f);
        uint bpk = pk2(bb, bb - lo_f32(bh));
        uint4 u;
        u.x = (g == 0) ? hab : (g == 1) ? lab : (g == 2) ? bpk : 0u;
        u.y = (g == 0) ? hcd : (g == 1) ? lcd : 0u;
        u.z = (g == 0) ? hab : (g == 1) ? lab : 0u;
        u.w = (g == 0) ? hcd : (g == 1) ? lcd : 0u;
        A1[nt] = as_s8(u);
    }

    // A2: w2^T hi in VGPR, lo to shared LDS
    uint4 A2h[2][2];
    #pragma unroll
    for (int mt = 0; mt < 2; ++mt) {
        int c = mt * 16 + l15;
        #pragma unroll
        for (int ks = 0; ks < 2; ++ks) {
            uint hu[4], lu[4];
            #pragma unroll
            for (int p = 0; p < 4; ++p) {
                int n = ks * 32 + g * 8 + 2 * p;
                float a = w2[n * 32 + c], b = w2[(n + 1) * 32 + c];
                uint h = pk2(a, b);
                hu[p] = h;
                lu[p] = pk2(a - lo_f32(h), b - hi_f32(h));
            }
            A2h[mt][ks] = make_uint4(hu[0], hu[1], hu[2], hu[3]);
            if (wv == 0) s_a2l[mt * 2 + ks][wl] = make_uint4(lu[0], lu[1], lu[2], lu[3]);
        }
    }

    f32x4 b2r[2];
    #pragma unroll
    for (int mt = 0; mt < 2; ++mt)
        b2r[mt] = *(const f32x4*)(b2 + 16 * mt + 4 * g);
    float2 w3r[8];
    #pragma unroll
    for (int mt = 0; mt < 2; ++mt)
        #pragma unroll
        for (int j = 0; j < 4; ++j)
            w3r[mt * 4 + j] = *(const float2*)(w3 + (16 * mt + 4 * g + j) * 2);
    const float b3g = b3[0], b3b = b3[1];

    __syncthreads();   // s_x, s_a2l ready

    // ---- chunk sums (10-wide) ----
    f32x4* s_chunk = s_buf;
    f32x4 myC[2];
    #pragma unroll
    for (int s = 0; s < 2; ++s) {
        int t = tid + 256 * s;
        float S1 = 0.f, S2 = 0.f, S3 = 0.f, S4 = 0.f;
        #pragma unroll
        for (int i = 0; i < 10; ++i) {
            float v = s_x[t + i], v2 = v * v;
            S1 += v; S2 += v2; S3 = fmaf(v2, v, S3); S4 = fmaf(v2, v2, S4);
        }
        myC[s] = f32x4{S1, S2, S3, S4};
        s_chunk[t] = myC[s];
    }
    if (tid < 40) {
        int t = tid + 512;
        float S1 = 0.f, S2 = 0.f, S3 = 0.f, S4 = 0.f;
        #pragma unroll
        for (int i = 0; i < 10; ++i) {
            float v = s_x[t + i], v2 = v * v;
            S1 += v; S2 += v2; S3 = fmaf(v2, v, S3); S4 = fmaf(v2, v2, S4);
        }
        s_chunk[t] = f32x4{S1, S2, S3, S4};
    }
    __syncthreads();   // chunks ready

    // ---- window moments; split-packed stats to per-wave LDS ----
    float nrm[2];
    #pragma unroll
    for (int s = 0; s < 2; ++s) {
        int t = tid + 256 * s;
        f32x4 ca = s_chunk[t + 10], cb = s_chunk[t + 20];
        f32x4 cc = s_chunk[t + 30], cd = s_chunk[t + 40];
        float S1 = myC[s][0] + ca[0] + cb[0] + cc[0] + cd[0];
        float S2 = myC[s][1] + ca[1] + cb[1] + cc[1] + cd[1];
        float S3 = myC[s][2] + ca[2] + cb[2] + cc[2] + cd[2];
        float S4 = myC[s][3] + ca[3] + cb[3] + cc[3] + cd[3];
        const float invW = 1.0f / (float)WINDOW;
        float mean = S1 * invW;
        float mu2  = mean * mean;
        float c2m = S2 - (float)WINDOW * mu2;
        float c3m = S3 - 3.0f * mean * S2 + 2.0f * (float)WINDOW * mu2 * mean;
        float c4m = S4 - 4.0f * mean * S3 + 6.0f * mu2 * S2
                      - 3.0f * (float)WINDOW * mu2 * mu2;
        float var    = c2m * (1.0f / (float)(WINDOW - 1));
        float sd     = sqrtf(var) + 1e-6f;
        float inv_sd = 1.0f / sd;
        float inv_sd2 = inv_sd * inv_sd;
        float skew = c3m * invW * inv_sd2 * inv_sd;
        float kurt = c4m * invW * inv_sd2 * inv_sd2;
        uint h01 = pk2(mean, sd), h23 = pk2(skew, kurt);
        uint l01 = pk2(mean - lo_f32(h01), sd - hi_f32(h01));
        uint l23 = pk2(skew - lo_f32(h23), kurt - hi_f32(h23));
        s_stat[wv][s * 64 + wl] = make_uint4(h01, h23, l01, l23);
        nrm[s] = (s_x[t + 25] - mean) * inv_sd;
    }
    __syncthreads();   // all chunk reads done -> s_buf reusable as h1

    // ---- quarter loop: L1 MFMA -> h1 split to LDS -> L2 MFMA -> L3 reduce ----
    uint* h1b = (uint*)(s_buf + wv * 272);   // per-wave: [win16][part2][32] pad to stride 68
    const uint K2 = (g == 2) ? 0x3F803F80u : 0u;   // (1.0,1.0) bf16 for bias row
    const bool gHi = (g >= 2);
    float ga[2] = {0.f, 0.f}, be[2] = {0.f, 0.f};

    #pragma unroll
    for (int q = 0; q < 8; ++q) {
        const int s = q >> 2, sub = q & 3;
        uint4 st = s_stat[wv][s * 64 + sub * 16 + l15];
        uint4 bq;
        bq.x = gHi ? K2 : st.x;
        bq.y = gHi ? 0u : st.y;
        bq.z = gHi ? 0u : st.z;
        bq.w = gHi ? 0u : st.w;
        short8 B1 = as_s8(bq);

        // L1 + split h1 (hi/lo) -> LDS, one nt at a time (short C1 lifetime)
        #pragma unroll
        for (int nt = 0; nt < 4; ++nt) {
            f32x4 c1 = f32x4{0.f, 0.f, 0.f, 0.f};
            c1 = __builtin_amdgcn_mfma_f32_16x16x32_bf16(A1[nt], B1, c1, 0, 0, 0);
            float r0 = fmaxf(c1[0], 0.f), r1 = fmaxf(c1[1], 0.f);
            float r2 = fmaxf(c1[2], 0.f), r3 = fmaxf(c1[3], 0.f);
            uint h01 = pk2(r0, r1), h23 = pk2(r2, r3);
            uint q01 = pk2(r0 - lo_f32(h01), r1 - hi_f32(h01));
            uint q23 = pk2(r2 - lo_f32(h23), r3 - hi_f32(h23));
            int d = l15 * 68 + 8 * nt + 2 * g;
            *(uint2*)&h1b[d]      = make_uint2(h01, h23);
            *(uint2*)&h1b[d + 32] = make_uint2(q01, q23);
        }
        __builtin_amdgcn_wave_barrier();   // keep compiler from hoisting reads above writes

        // B2 fragments (same-wave in-order DS pipe -> no block barrier needed)
        short8 Bh0 = as_s8(*(uint4*)&h1b[l15 * 68 +  0 + 4 * g]);
        short8 Bh1 = as_s8(*(uint4*)&h1b[l15 * 68 + 16 + 4 * g]);
        short8 Bl0 = as_s8(*(uint4*)&h1b[l15 * 68 + 32 + 4 * g]);
        short8 Bl1 = as_s8(*(uint4*)&h1b[l15 * 68 + 48 + 4 * g]);

        // L2 (exact: hi*hi + hi*lo + lo*hi) then L3 partials, one mt at a time
        float pg = 0.f, pb = 0.f;
        #pragma unroll
        for (int mt = 0; mt < 2; ++mt) {
            short8 a2l0 = as_s8(s_a2l[mt * 2 + 0][wl]);
            short8 a2l1 = as_s8(s_a2l[mt * 2 + 1][wl]);
            f32x4 c2 = b2r[mt];
            c2 = __builtin_amdgcn_mfma_f32_16x16x32_bf16(as_s8(A2h[mt][0]), Bh0, c2, 0, 0, 0);
            c2 = __builtin_amdgcn_mfma_f32_16x16x32_bf16(as_s8(A2h[mt][1]), Bh1, c2, 0, 0, 0);
            c2 = __builtin_amdgcn_mfma_f32_16x16x32_bf16(as_s8(A2h[mt][0]), Bl0, c2, 0, 0, 0);
            c2 = __builtin_amdgcn_mfma_f32_16x16x32_bf16(as_s8(A2h[mt][1]), Bl1, c2, 0, 0, 0);
            c2 = __builtin_amdgcn_mfma_f32_16x16x32_bf16(a2l0, Bh0, c2, 0, 0, 0);
            c2 = __builtin_amdgcn_mfma_f32_16x16x32_bf16(a2l1, Bh1, c2, 0, 0, 0);
            #pragma unroll
            for (int j = 0; j < 4; ++j) {
                float P = fmaxf(c2[j], 0.f);
                float2 w = w3r[mt * 4 + j];
                pg = fmaf(P, w.x, pg);
                pb = fmaf(P, w.y, pb);
            }
        }
        // reduce over the 4 lane-groups sharing l15 (fp32, exact w3)
        pg += __shfl_xor(pg, 16);
        pb += __shfl_xor(pb, 16);
        pg += __shfl_xor(pg, 32);
        pb += __shfl_xor(pb, 32);
        if (g == sub) { ga[s] = pg; be[s] = pb; }
    }

    // ---- epilogue ----
    #pragma unroll
    for (int s = 0; s < 2; ++s) {
        int m = m0 + tid + 256 * s;
        if (m < M)
            out[(size_t)row * M + m] = fmaf(nrm[s], ga[s] + b3g, be[s] + b3b);
    }
}

extern "C" void kernel_launch(void* const* d_in, const int* in_sizes, int n_in,
                              void* d_out, int out_size, void* d_ws, size_t ws_size,
                              hipStream_t stream) {
    const float* x  = (const float*)d_in[0];
    const float* w1 = (const float*)d_in[1];
    const float* b1 = (const float*)d_in[2];
    const float* w2 = (const float*)d_in[3];
    const float* b2 = (const float*)d_in[4];
    const float* w3 = (const float*)d_in[5];
    const float* b3 = (const float*)d_in[6];
    float* out = (float*)d_out;

    const int N = 32768;
    const int B = in_sizes[0] / N;           // 32
    const int M = N - WINDOW + 1;            // 32719
    const int tiles = (M + 511) / 512;       // 64

    dim3 grid(B * tiles), block(256);
    nsg_kernel<<<grid, block, 0, stream>>>(x, w1, b1, w2, b2, w3, b3,
                                           out, N, M, tiles);
}